// Round 8
// baseline (929.815 us; speedup 1.0000x reference)
//
#include <hip/hip_runtime.h>
#include <stdint.h>

#define N_PTS 16384
#define TAU_C 0.001f
#define N_ITER 10

// ---- spatial grid over targets ----
#define G 72
#define NCELLS (G * G * G)              // 373248
#define XMIN (-6.0f)
#define CELL_H (12.0f / (float)G)       // 0.16667
#define INV_H ((float)G / 12.0f)
#define NSCAN ((NCELLS + 1023) / 1024)  // 365 scan blocks (256 thr x 4 items)
#define KMAX 2                           // shell cap; unresolved -> brute fallback
#define NACC 64                          // accum blocks
#define NBRUTE_BLOCKS 128                // 512 waves for fallback

struct State {
  float x[6];    // accepted params
  float xc[6];   // candidate params
  float dx[6];   // last step
  float Rc[9];   // candidate rotation (row-major)
  float tc[3];   // candidate translation
  float H[21];   // accepted J^T J, upper triangle
  float g[6];    // accepted J^T r
  float F, mu, nu;
};

// ---------------- se3 exp (matches reference formulas, fp32) ----------------
__device__ void se3_exp_rt(const float* x, float* R, float* t) {
  float wx = x[0], wy = x[1], wz = x[2];
  float vx = x[3], vy = x[4], vz = x[5];
  float th2 = wx*wx + wy*wy + wz*wz;
  float th = sqrtf(th2);
  float A, B, C;
  if (th < 1e-8f) {
    A = 1.0f - th2 / 6.0f;
    B = 0.5f - th2 / 24.0f;
    C = 1.0f / 6.0f - th2 / 120.0f;
  } else {
    float s = sinf(th), c = cosf(th);
    A = s / th;
    B = (1.0f - c) / th2;
    C = (th - s) / (th2 * th);
  }
  float W[9]  = {0.f, -wz, wy,  wz, 0.f, -wx,  -wy, wx, 0.f};
  float W2[9];
  #pragma unroll
  for (int r = 0; r < 3; r++)
    #pragma unroll
    for (int c = 0; c < 3; c++)
      W2[3*r+c] = W[3*r+0]*W[0+c] + W[3*r+1]*W[3+c] + W[3*r+2]*W[6+c];
  float V[9];
  #pragma unroll
  for (int k = 0; k < 9; k++) {
    float I = (k == 0 || k == 4 || k == 8) ? 1.f : 0.f;
    R[k] = I + A * W[k] + B * W2[k];
    V[k] = I + B * W[k] + C * W2[k];
  }
  t[0] = V[0]*vx + V[1]*vy + V[2]*vz;
  t[1] = V[3]*vx + V[4]*vy + V[5]*vz;
  t[2] = V[6]*vx + V[7]*vy + V[8]*vz;
}

__device__ inline int cell1d(float v) {
  int c = (int)floorf((v - XMIN) * INV_H);
  return min(max(c, 0), G - 1);
}

__device__ inline unsigned monoF(float f) {
  unsigned u = __float_as_uint(f);
  return (u & 0x80000000u) ? ~u : (u | 0x80000000u);
}

// ---------------- prep 1: zero counts, init counters + state ----------------
__global__ __launch_bounds__(256) void zero_kernel(unsigned* __restrict__ count,
                                                   unsigned* __restrict__ counter,
                                                   unsigned* __restrict__ fbCount,
                                                   State* st) {
  unsigned idx = blockIdx.x * 256u + threadIdx.x;
  if (idx < NCELLS) count[idx] = 0u;
  if (idx == 0) {
    #pragma unroll
    for (int k = 0; k < 6; k++) { st->x[k] = 0.f; st->xc[k] = 0.f; st->dx[k] = 0.f; }
    #pragma unroll
    for (int k = 0; k < 9; k++) st->Rc[k] = (k % 4 == 0) ? 1.f : 0.f;
    st->tc[0] = st->tc[1] = st->tc[2] = 0.f;
    st->nu = 2.f;
    *counter = 0u;
    *fbCount = 0u;
  }
}

// ---------------- prep 2: histogram targets into cells + pack for brute ----------------
__global__ __launch_bounds__(256) void count_kernel(const float* __restrict__ trg,
                                                    unsigned* __restrict__ count,
                                                    float4* __restrict__ packed) {
  int j = blockIdx.x * 256 + threadIdx.x;
  float tx = trg[3*j], ty = trg[3*j+1], tz = trg[3*j+2];
  packed[j] = make_float4(-2.f*tx, -2.f*ty, -2.f*tz, tx*tx + ty*ty + tz*tz);
  int cx = cell1d(tx), cy = cell1d(ty), cz = cell1d(tz);
  atomicAdd(&count[(cz * G + cy) * G + cx], 1u);
}

// ---------------- prep 3: block-local exclusive scan (1024 items/block) ----------------
__global__ __launch_bounds__(256) void scan1_kernel(const unsigned* __restrict__ count,
                                                    unsigned* __restrict__ excl,
                                                    unsigned* __restrict__ blockSums) {
  __shared__ unsigned sh[256];
  const int t = threadIdx.x;
  const unsigned base = blockIdx.x * 1024u + t * 4u;
  unsigned v0 = (base + 0 < NCELLS) ? count[base + 0] : 0u;
  unsigned v1 = (base + 1 < NCELLS) ? count[base + 1] : 0u;
  unsigned v2 = (base + 2 < NCELLS) ? count[base + 2] : 0u;
  unsigned v3 = (base + 3 < NCELLS) ? count[base + 3] : 0u;
  unsigned tsum = v0 + v1 + v2 + v3;
  sh[t] = tsum;
  __syncthreads();
  for (int off = 1; off < 256; off <<= 1) {
    unsigned xv = (t >= off) ? sh[t - off] : 0u;
    __syncthreads();
    sh[t] += xv;
    __syncthreads();
  }
  unsigned texcl = sh[t] - tsum;
  if (t == 255) blockSums[blockIdx.x] = sh[255];
  if (base + 0 < NCELLS) excl[base + 0] = texcl;
  if (base + 1 < NCELLS) excl[base + 1] = texcl + v0;
  if (base + 2 < NCELLS) excl[base + 2] = texcl + v0 + v1;
  if (base + 3 < NCELLS) excl[base + 3] = texcl + v0 + v1 + v2;
}

// ---------------- prep 4: scan the 365 block sums (single block) ----------------
__global__ __launch_bounds__(512) void scan2_kernel(unsigned* __restrict__ blockSums) {
  __shared__ unsigned sh[512];
  int t = threadIdx.x;
  unsigned v = (t < NSCAN) ? blockSums[t] : 0u;
  sh[t] = v;
  __syncthreads();
  for (int off = 1; off < 512; off <<= 1) {
    unsigned xv = (t >= off) ? sh[t - off] : 0u;
    __syncthreads();
    sh[t] += xv;
    __syncthreads();
  }
  if (t < NSCAN) blockSums[t] = sh[t] - v;   // exclusive
}

// ---------------- prep 5: finalize starts; pack (start<<8 | count); init cursor ----------------
__global__ __launch_bounds__(256) void scan3_kernel(const unsigned* __restrict__ count,
                                                    unsigned* __restrict__ cursor,
                                                    const unsigned* __restrict__ blockSums,
                                                    unsigned* __restrict__ gridPacked) {
  const unsigned base = blockIdx.x * 1024u + threadIdx.x * 4u;
  unsigned boff = blockSums[blockIdx.x];
  #pragma unroll
  for (int q = 0; q < 4; q++) {
    unsigned idx = base + q;
    if (idx < NCELLS) {
      unsigned start = cursor[idx] + boff;
      unsigned n = count[idx]; n = n > 255u ? 255u : n;
      gridPacked[idx] = (start << 8) | n;
      cursor[idx] = start;
    }
  }
}

// ---------------- prep 6: scatter targets into sorted order ----------------
__global__ __launch_bounds__(256) void scatter_kernel(const float* __restrict__ trg,
                                                      unsigned* __restrict__ cursor,
                                                      float4* __restrict__ sortedPts,
                                                      unsigned* __restrict__ sortedIdx) {
  int j = blockIdx.x * 256 + threadIdx.x;
  float tx = trg[3*j], ty = trg[3*j+1], tz = trg[3*j+2];
  int cx = cell1d(tx), cy = cell1d(ty), cz = cell1d(tz);
  unsigned pos = atomicAdd(&cursor[(cz * G + cy) * G + cx], 1u);
  sortedPts[pos] = make_float4(tx, ty, tz, __uint_as_float((unsigned)j));
  sortedIdx[pos] = (unsigned)j;
}

// ---------- eval A: grid NN with shell cap; unresolved -> fallback list ----------
__global__ __launch_bounds__(256) void nn_grid_kernel(const float* __restrict__ ref,
                                                      const unsigned* __restrict__ gridPacked,
                                                      const float4* __restrict__ sortedPts,
                                                      const unsigned* __restrict__ sortedIdx,
                                                      const State* __restrict__ st,
                                                      unsigned long long* __restrict__ keys,
                                                      unsigned* __restrict__ fbList,
                                                      unsigned* __restrict__ fbCount) {
  const int it = blockIdx.x * 256 + threadIdx.x;
  const int i = (int)sortedIdx[it];          // spatially-sorted query order

  const float R00 = st->Rc[0], R01 = st->Rc[1], R02 = st->Rc[2];
  const float R10 = st->Rc[3], R11 = st->Rc[4], R12 = st->Rc[5];
  const float R20 = st->Rc[6], R21 = st->Rc[7], R22 = st->Rc[8];
  const float t0 = st->tc[0], t1 = st->tc[1], t2 = st->tc[2];

  const float rx = ref[3*i], ry = ref[3*i+1], rz = ref[3*i+2];
  const float ax = rx - t0, ay = ry - t1, az = rz - t2;
  const float qx = R00*ax + R10*ay + R20*az;
  const float qy = R01*ax + R11*ay + R21*az;
  const float qz = R02*ax + R12*ay + R22*az;

  const int gx = cell1d(qx), gy = cell1d(qy), gz = cell1d(qz);

  float best = 3.4e38f;
  int bj = 0x7FFFFFFF;
  bool done = false;
  for (int k = 0; k <= KMAX && !done; k++) {
    for (int dz = -k; dz <= k; dz++) {
      int cz = gz + dz;
      if ((unsigned)cz >= (unsigned)G) continue;
      bool zface = (dz == -k) || (dz == k);
      for (int dy = -k; dy <= k; dy++) {
        int cy = gy + dy;
        if ((unsigned)cy >= (unsigned)G) continue;
        bool face = zface || (dy == -k) || (dy == k);
        int step = face ? 1 : (2 * k);
        for (int dx = -k; dx <= k; dx += step) {
          int cx = gx + dx;
          if ((unsigned)cx >= (unsigned)G) continue;
          unsigned pc = gridPacked[(cz * G + cy) * G + cx];
          unsigned s = pc >> 8, n = pc & 255u;
          for (unsigned c = 0; c < n; c++) {
            float4 p = sortedPts[s + c];
            float ddx = qx - p.x, ddy = qy - p.y, ddz = qz - p.z;
            float d2 = fmaf(ddz, ddz, fmaf(ddy, ddy, ddx * ddx));
            int jj = (int)__float_as_uint(p.w);
            if (d2 < best || (d2 == best && jj < bj)) { best = d2; bj = jj; }
          }
        }
      }
    }
    // distance from q to nearest unscanned cell face (grid-edge faces excluded:
    // out-of-bbox points are clamped into edge cells, which the window covers)
    float dmin = 3.4e38f;
    if (gx - k > 0)     dmin = fminf(dmin, qx - (XMIN + (float)(gx - k) * CELL_H));
    if (gx + k < G - 1) dmin = fminf(dmin, (XMIN + (float)(gx + k + 1) * CELL_H) - qx);
    if (gy - k > 0)     dmin = fminf(dmin, qy - (XMIN + (float)(gy - k) * CELL_H));
    if (gy + k < G - 1) dmin = fminf(dmin, (XMIN + (float)(gy + k + 1) * CELL_H) - qy);
    if (gz - k > 0)     dmin = fminf(dmin, qz - (XMIN + (float)(gz - k) * CELL_H));
    if (gz + k < G - 1) dmin = fminf(dmin, (XMIN + (float)(gz + k + 1) * CELL_H) - qz);
    if (best <= dmin * dmin) done = true;
  }

  if (done) {
    keys[i] = ((unsigned long long)monoF(best) << 32) | (unsigned long long)(unsigned)bj;
  } else {
    unsigned pos = atomicAdd(fbCount, 1u);
    fbList[pos] = (unsigned)i;
  }
}

// ---------- eval B: brute-force fallback queries, one wave per query ----------
__global__ __launch_bounds__(256) void nn_brute_kernel(const float* __restrict__ ref,
                                                       const float4* __restrict__ packed,
                                                       const State* __restrict__ st,
                                                       unsigned long long* __restrict__ keys,
                                                       const unsigned* __restrict__ fbList,
                                                       const unsigned* __restrict__ fbCount) {
  const int lane = threadIdx.x & 63;
  const int wid = (blockIdx.x * 256 + threadIdx.x) >> 6;
  const int nWaves = NBRUTE_BLOCKS * 4;
  const unsigned n = *fbCount;

  const float R00 = st->Rc[0], R01 = st->Rc[1], R02 = st->Rc[2];
  const float R10 = st->Rc[3], R11 = st->Rc[4], R12 = st->Rc[5];
  const float R20 = st->Rc[6], R21 = st->Rc[7], R22 = st->Rc[8];
  const float t0 = st->tc[0], t1 = st->tc[1], t2 = st->tc[2];

  for (unsigned e = wid; e < n; e += nWaves) {
    int i = (int)fbList[e];
    float ax = ref[3*i] - t0, ay = ref[3*i+1] - t1, az = ref[3*i+2] - t2;
    float qx = R00*ax + R10*ay + R20*az;
    float qy = R01*ax + R11*ay + R21*az;
    float qz = R02*ax + R12*ay + R22*az;

    unsigned long long bkey = 0xFFFFFFFFFFFFFFFFULL;
    for (int jj = lane; jj < N_PTS; jj += 64) {
      float4 tq = packed[jj];
      // score = |t|^2 - 2 q.t (row-constant |q|^2 omitted; argmin unchanged)
      float s = fmaf(qx, tq.x, tq.w);
      s = fmaf(qy, tq.y, s);
      s = fmaf(qz, tq.z, s);
      unsigned long long key = ((unsigned long long)monoF(s) << 32) |
                               (unsigned long long)(unsigned)jj;
      bkey = key < bkey ? key : bkey;
    }
    #pragma unroll
    for (int off = 32; off; off >>= 1) {
      unsigned long long o = __shfl_xor(bkey, off, 64);
      bkey = o < bkey ? o : bkey;
    }
    if (lane == 0) keys[i] = bkey;
  }
}

// -------- eval C: accumulate H,g,F (double) + last-block LM --------
__global__ __launch_bounds__(256) void accum_lm_kernel(const float* __restrict__ ref,
                                                       const float* __restrict__ trg,
                                                       const float* __restrict__ nrm,
                                                       const unsigned long long* __restrict__ keys,
                                                       State* st,
                                                       double* __restrict__ partials,
                                                       unsigned* __restrict__ counter,
                                                       unsigned* __restrict__ fbCount,
                                                       float* out, int mode) {
  const int tid = threadIdx.x;
  const int i = blockIdx.x * 256 + tid;

  const float R00 = st->Rc[0], R01 = st->Rc[1], R02 = st->Rc[2];
  const float R10 = st->Rc[3], R11 = st->Rc[4], R12 = st->Rc[5];
  const float R20 = st->Rc[6], R21 = st->Rc[7], R22 = st->Rc[8];
  const float t0 = st->tc[0], t1 = st->tc[1], t2 = st->tc[2];

  int j = (int)(unsigned)(keys[i] & 0xFFFFFFFFULL);

  float nx0 = nrm[3*j], ny0 = nrm[3*j+1], nz0 = nrm[3*j+2];
  float sx = trg[3*j], sy = trg[3*j+1], sz = trg[3*j+2];
  float nx = R00*nx0 + R01*ny0 + R02*nz0;
  float ny = R10*nx0 + R11*ny0 + R12*nz0;
  float nz = R20*nx0 + R21*ny0 + R22*nz0;
  float pxx = R00*sx + R01*sy + R02*sz + t0;
  float pyy = R10*sx + R11*sy + R12*sz + t1;
  float pzz = R20*sx + R21*sy + R22*sz + t2;

  float rx = ref[3*i], ry = ref[3*i+1], rz = ref[3*i+2];
  float dxx = rx - pxx, dyy = ry - pyy, dzz = rz - pzz;
  float r = nx*dxx + ny*dyy + nz*dzz;

  float J[6];
  J[0] = ry*nz - rz*ny;
  J[1] = rz*nx - rx*nz;
  J[2] = rx*ny - ry*nx;
  J[3] = nx; J[4] = ny; J[5] = nz;

  double acc[28];
  int c21 = 0;
  #pragma unroll
  for (int a = 0; a < 6; a++)
    #pragma unroll
    for (int b = a; b < 6; b++)
      acc[c21++] = (double)J[a] * (double)J[b];
  #pragma unroll
  for (int a = 0; a < 6; a++) acc[21+a] = (double)J[a] * (double)r;
  acc[27] = (double)r * (double)r;

  #pragma unroll
  for (int kk = 0; kk < 28; kk++) {
    double v = acc[kk];
    for (int off = 32; off; off >>= 1) v += __shfl_down(v, off);
    acc[kk] = v;
  }
  __shared__ double redD[4][28];
  int wave = tid >> 6, lane = tid & 63;
  if (lane == 0) {
    #pragma unroll
    for (int kk = 0; kk < 28; kk++) redD[wave][kk] = acc[kk];
  }
  __syncthreads();
  if (tid < 28)
    partials[tid * NACC + blockIdx.x] =
        redD[0][tid] + redD[1][tid] + redD[2][tid] + redD[3][tid];

  // ---- last-block-does-LM ----
  __shared__ bool last;
  __syncthreads();
  if (tid == 0) {
    __threadfence();
    unsigned old = atomicAdd(counter, 1u);
    last = (old == NACC - 1);
  }
  __syncthreads();
  if (!last) return;

  __threadfence();
  __shared__ float tot[28];
  if (tid < 28) {
    double s = 0.0;
    #pragma unroll
    for (int b = 0; b < NACC; b++) s += partials[tid * NACC + b];  // fixed order
    tot[tid] = (float)s;
  }
  __syncthreads();

  if (tid == 0) {
    atomicExch(counter, 0u);           // reset for next eval
    atomicExch(fbCount, 0u);           // reset fallback list for next eval
    float Fn = tot[27];
    float mu, nu;

    if (mode == 0) {
      #pragma unroll
      for (int k = 0; k < 6; k++) st->x[k] = st->xc[k];
      #pragma unroll
      for (int k = 0; k < 21; k++) st->H[k] = tot[k];
      #pragma unroll
      for (int k = 0; k < 6; k++) st->g[k] = tot[21+k];
      st->F = Fn;
      float md = tot[0];
      md = fmaxf(md, tot[6]); md = fmaxf(md, tot[11]); md = fmaxf(md, tot[15]);
      md = fmaxf(md, tot[18]); md = fmaxf(md, tot[20]);
      mu = TAU_C * md;
      nu = 2.f;
    } else {
      mu = st->mu; nu = st->nu;
      float denom = 0.f;
      #pragma unroll
      for (int k = 0; k < 6; k++) denom += st->dx[k] * (mu * st->dx[k] - st->g[k]);
      if (fabsf(denom) < 1e-12f) denom = 1e-12f;
      float rho = (st->F - Fn) / denom;
      if (rho > 0.f) {
        #pragma unroll
        for (int k = 0; k < 6; k++) st->x[k] = st->xc[k];
        #pragma unroll
        for (int k = 0; k < 21; k++) st->H[k] = tot[k];
        #pragma unroll
        for (int k = 0; k < 6; k++) st->g[k] = tot[21+k];
        st->F = Fn;
        float tcube = 2.f * rho - 1.f;
        mu = mu * fmaxf(1.f / 3.f, 1.f - tcube * tcube * tcube);
        nu = 2.f;
      } else {
        mu = mu * nu;
        nu = 2.f * nu;
      }
    }
    st->mu = mu; st->nu = nu;

    if (mode < N_ITER) {
      // solve (H + mu I) d = -g ; SPD -> unpivoted Gauss, fully unrolled
      float A[6][7];
      int c21b = 0;
      #pragma unroll
      for (int a = 0; a < 6; a++)
        #pragma unroll
        for (int b = a; b < 6; b++) { A[a][b] = st->H[c21b]; A[b][a] = st->H[c21b]; c21b++; }
      #pragma unroll
      for (int a = 0; a < 6; a++) { A[a][a] += mu; A[a][6] = -st->g[a]; }
      #pragma unroll
      for (int col = 0; col < 6; col++) {
        float inv = 1.f / A[col][col];
        #pragma unroll
        for (int rI = 0; rI < 6; rI++) {
          if (rI > col) {
            float f = A[rI][col] * inv;
            #pragma unroll
            for (int cc = 0; cc < 7; cc++)
              if (cc >= col) A[rI][cc] -= f * A[col][cc];
          }
        }
      }
      float d[6];
      #pragma unroll
      for (int rI = 5; rI >= 0; rI--) {
        float s = A[rI][6];
        #pragma unroll
        for (int cc = 0; cc < 6; cc++)
          if (cc > rI) s -= A[rI][cc] * d[cc];
        d[rI] = s / A[rI][rI];
      }
      float Rn[9], tn[3];
      #pragma unroll
      for (int k = 0; k < 6; k++) { st->dx[k] = d[k]; st->xc[k] = st->x[k] + d[k]; }
      se3_exp_rt(st->xc, Rn, tn);
      #pragma unroll
      for (int k = 0; k < 9; k++) st->Rc[k] = Rn[k];
      #pragma unroll
      for (int k = 0; k < 3; k++) st->tc[k] = tn[k];
    } else {
      float Rn[9], tn[3];
      se3_exp_rt(st->x, Rn, tn);
      out[0] = Rn[0]; out[1] = Rn[1]; out[2]  = Rn[2]; out[3]  = tn[0];
      out[4] = Rn[3]; out[5] = Rn[4]; out[6]  = Rn[5]; out[7]  = tn[1];
      out[8] = Rn[6]; out[9] = Rn[7]; out[10] = Rn[8]; out[11] = tn[2];
      out[12] = 0.f; out[13] = 0.f; out[14] = 0.f; out[15] = 1.f;
      out[16] = st->F / (float)N_PTS;
    }
  }
}

extern "C" void kernel_launch(void* const* d_in, const int* in_sizes, int n_in,
                              void* d_out, int out_size, void* d_ws, size_t ws_size,
                              hipStream_t stream) {
  const float* ref = (const float*)d_in[0];
  const float* trg = (const float*)d_in[1];
  const float* nrm = (const float*)d_in[2];
  float* out = (float*)d_out;

  char* ws = (char*)d_ws;
  unsigned* count      = (unsigned*)(ws);                       // 1,492,992 B
  unsigned* gridPacked = (unsigned*)(ws + 1492992);             // 1,492,992 B
  unsigned* cursor     = (unsigned*)(ws + 2985984);             // 1,492,992 B
  unsigned* blockSums  = (unsigned*)(ws + 4478976);             // 2,048 B
  float4*   sortedPts  = (float4*)  (ws + 4481024);             // 262,144 B
  unsigned* sortedIdx  = (unsigned*)(ws + 4743168);             // 65,536 B
  float4*   packed     = (float4*)  (ws + 4808704);             // 262,144 B
  unsigned long long* keys = (unsigned long long*)(ws + 5070848); // 131,072 B
  unsigned* fbList     = (unsigned*)(ws + 5201920);             // 65,536 B
  double*   partials   = (double*)  (ws + 5267456);             // 14,336 B
  unsigned* counter    = (unsigned*)(ws + 5281792);
  unsigned* fbCount    = (unsigned*)(ws + 5281856);
  State*    st         = (State*)   (ws + 5281920);

  // build grid over targets (once) + init LM state
  zero_kernel   <<<(NCELLS + 255) / 256, 256, 0, stream>>>(count, counter, fbCount, st);
  count_kernel  <<<N_PTS / 256, 256, 0, stream>>>(trg, count, packed);
  scan1_kernel  <<<NSCAN, 256, 0, stream>>>(count, cursor, blockSums);
  scan2_kernel  <<<1, 512, 0, stream>>>(blockSums);
  scan3_kernel  <<<NSCAN, 256, 0, stream>>>(count, cursor, blockSums, gridPacked);
  scatter_kernel<<<N_PTS / 256, 256, 0, stream>>>(trg, cursor, sortedPts, sortedIdx);

  for (int e = 0; e <= N_ITER; e++) {
    nn_grid_kernel <<<N_PTS / 256, 256, 0, stream>>>(ref, gridPacked, sortedPts,
                                                     sortedIdx, st, keys, fbList, fbCount);
    nn_brute_kernel<<<NBRUTE_BLOCKS, 256, 0, stream>>>(ref, packed, st, keys,
                                                       fbList, fbCount);
    accum_lm_kernel<<<NACC, 256, 0, stream>>>(ref, trg, nrm, keys, st, partials,
                                              counter, fbCount, out, e);
  }
}

// Round 9
// 394.660 us; speedup vs baseline: 2.3560x; 2.3560x over previous
//
#include <hip/hip_runtime.h>
#include <stdint.h>

#define N_PTS 16384
#define TAU_C 0.001f
#define N_ITER 10

// ---- spatial grid over targets ----
#define G 48
#define NCELLS (G * G * G)              // 110592
#define XMIN (-6.0f)
#define CELL_H 0.25f
#define INV_H 4.0f
#define NSCAN ((NCELLS + 1023) / 1024)  // 108 scan blocks (256 thr x 4 items)
#define GS 8                             // lanes cooperating per query
#define QPB (256 / GS)                   // 32 queries per block
#define NEVAL (N_PTS / QPB)              // 512 eval blocks

struct State {
  float x[6];    // accepted params
  float xc[6];   // candidate params
  float dx[6];   // last step
  float Rc[9];   // candidate rotation (row-major)
  float tc[3];   // candidate translation
  float H[21];   // accepted J^T J, upper triangle
  float g[6];    // accepted J^T r
  float F, mu, nu;
};

// ---------------- se3 exp (matches reference formulas, fp32) ----------------
__device__ void se3_exp_rt(const float* x, float* R, float* t) {
  float wx = x[0], wy = x[1], wz = x[2];
  float vx = x[3], vy = x[4], vz = x[5];
  float th2 = wx*wx + wy*wy + wz*wz;
  float th = sqrtf(th2);
  float A, B, C;
  if (th < 1e-8f) {
    A = 1.0f - th2 / 6.0f;
    B = 0.5f - th2 / 24.0f;
    C = 1.0f / 6.0f - th2 / 120.0f;
  } else {
    float s = sinf(th), c = cosf(th);
    A = s / th;
    B = (1.0f - c) / th2;
    C = (th - s) / (th2 * th);
  }
  float W[9]  = {0.f, -wz, wy,  wz, 0.f, -wx,  -wy, wx, 0.f};
  float W2[9];
  #pragma unroll
  for (int r = 0; r < 3; r++)
    #pragma unroll
    for (int c = 0; c < 3; c++)
      W2[3*r+c] = W[3*r+0]*W[0+c] + W[3*r+1]*W[3+c] + W[3*r+2]*W[6+c];
  float V[9];
  #pragma unroll
  for (int k = 0; k < 9; k++) {
    float I = (k == 0 || k == 4 || k == 8) ? 1.f : 0.f;
    R[k] = I + A * W[k] + B * W2[k];
    V[k] = I + B * W[k] + C * W2[k];
  }
  t[0] = V[0]*vx + V[1]*vy + V[2]*vz;
  t[1] = V[3]*vx + V[4]*vy + V[5]*vz;
  t[2] = V[6]*vx + V[7]*vy + V[8]*vz;
}

__device__ inline int cell1d(float v) {
  int c = (int)floorf((v - XMIN) * INV_H);
  return min(max(c, 0), G - 1);
}

// ---------------- prep 1: zero counts, init counter + state ----------------
__global__ __launch_bounds__(256) void zero_kernel(unsigned* __restrict__ count,
                                                   unsigned* __restrict__ counter,
                                                   State* st) {
  unsigned idx = blockIdx.x * 256u + threadIdx.x;
  if (idx < NCELLS) count[idx] = 0u;
  if (idx == 0) {
    #pragma unroll
    for (int k = 0; k < 6; k++) { st->x[k] = 0.f; st->xc[k] = 0.f; st->dx[k] = 0.f; }
    #pragma unroll
    for (int k = 0; k < 9; k++) st->Rc[k] = (k % 4 == 0) ? 1.f : 0.f;
    st->tc[0] = st->tc[1] = st->tc[2] = 0.f;
    st->nu = 2.f;
    *counter = 0u;
  }
}

// ---------------- prep 2: histogram targets into cells ----------------
__global__ __launch_bounds__(256) void count_kernel(const float* __restrict__ trg,
                                                    unsigned* __restrict__ count) {
  int j = blockIdx.x * 256 + threadIdx.x;
  int cx = cell1d(trg[3*j]), cy = cell1d(trg[3*j+1]), cz = cell1d(trg[3*j+2]);
  atomicAdd(&count[(cz * G + cy) * G + cx], 1u);
}

// ---------------- prep 3: block-local exclusive scan (1024 items/block) ----------------
__global__ __launch_bounds__(256) void scan1_kernel(const unsigned* __restrict__ count,
                                                    unsigned* __restrict__ excl,
                                                    unsigned* __restrict__ blockSums) {
  __shared__ unsigned sh[256];
  const int t = threadIdx.x;
  const unsigned base = blockIdx.x * 1024u + t * 4u;
  unsigned v0 = (base + 0 < NCELLS) ? count[base + 0] : 0u;
  unsigned v1 = (base + 1 < NCELLS) ? count[base + 1] : 0u;
  unsigned v2 = (base + 2 < NCELLS) ? count[base + 2] : 0u;
  unsigned v3 = (base + 3 < NCELLS) ? count[base + 3] : 0u;
  unsigned tsum = v0 + v1 + v2 + v3;
  sh[t] = tsum;
  __syncthreads();
  for (int off = 1; off < 256; off <<= 1) {
    unsigned xv = (t >= off) ? sh[t - off] : 0u;
    __syncthreads();
    sh[t] += xv;
    __syncthreads();
  }
  unsigned texcl = sh[t] - tsum;
  if (t == 255) blockSums[blockIdx.x] = sh[255];
  if (base + 0 < NCELLS) excl[base + 0] = texcl;
  if (base + 1 < NCELLS) excl[base + 1] = texcl + v0;
  if (base + 2 < NCELLS) excl[base + 2] = texcl + v0 + v1;
  if (base + 3 < NCELLS) excl[base + 3] = texcl + v0 + v1 + v2;
}

// ---------------- prep 4: scan the 108 block sums (single block) ----------------
__global__ __launch_bounds__(512) void scan2_kernel(unsigned* __restrict__ blockSums) {
  __shared__ unsigned sh[512];
  int t = threadIdx.x;
  unsigned v = (t < NSCAN) ? blockSums[t] : 0u;
  sh[t] = v;
  __syncthreads();
  for (int off = 1; off < 512; off <<= 1) {
    unsigned xv = (t >= off) ? sh[t - off] : 0u;
    __syncthreads();
    sh[t] += xv;
    __syncthreads();
  }
  if (t < NSCAN) blockSums[t] = sh[t] - v;   // exclusive
}

// ---------------- prep 5: finalize starts; pack (start<<8 | count); init cursor ----------------
__global__ __launch_bounds__(256) void scan3_kernel(const unsigned* __restrict__ count,
                                                    unsigned* __restrict__ cursor,
                                                    const unsigned* __restrict__ blockSums,
                                                    unsigned* __restrict__ gridPacked) {
  const unsigned base = blockIdx.x * 1024u + threadIdx.x * 4u;
  unsigned boff = blockSums[blockIdx.x];
  #pragma unroll
  for (int q = 0; q < 4; q++) {
    unsigned idx = base + q;
    if (idx < NCELLS) {
      unsigned start = cursor[idx] + boff;
      unsigned n = count[idx]; n = n > 255u ? 255u : n;
      gridPacked[idx] = (start << 8) | n;
      cursor[idx] = start;
    }
  }
}

// ---------------- prep 6: scatter targets into sorted order ----------------
__global__ __launch_bounds__(256) void scatter_kernel(const float* __restrict__ trg,
                                                      unsigned* __restrict__ cursor,
                                                      float4* __restrict__ sortedPts,
                                                      unsigned* __restrict__ sortedIdx) {
  int j = blockIdx.x * 256 + threadIdx.x;
  float tx = trg[3*j], ty = trg[3*j+1], tz = trg[3*j+2];
  int cx = cell1d(tx), cy = cell1d(ty), cz = cell1d(tz);
  unsigned pos = atomicAdd(&cursor[(cz * G + cy) * G + cx], 1u);
  sortedPts[pos] = make_float4(tx, ty, tz, __uint_as_float((unsigned)j));
  sortedIdx[pos] = (unsigned)j;
}

// ======== fused eval: 8-lane-per-query grid NN + accumulate + last-block LM ========
// Exact NN: scan full box radius r (lanes stride cells; rescans are idempotent
// under 64-bit key min), group-reduce (d2bits<<32|j) via shfl_xor, stop when
// best <= (distance to nearest unscanned face)^2. d2>=0 so raw float bits
// order as uint; low-bits j gives smallest-index tie-break (== jnp.argmin).
__global__ __launch_bounds__(256) void eval_kernel(const float* __restrict__ ref,
                                                   const float* __restrict__ trg,
                                                   const float* __restrict__ nrm,
                                                   const unsigned* __restrict__ gridPacked,
                                                   const float4* __restrict__ sortedPts,
                                                   const unsigned* __restrict__ sortedIdx,
                                                   State* st,
                                                   double* __restrict__ partials,
                                                   unsigned* __restrict__ counter,
                                                   float* out, int mode) {
  const int tid = threadIdx.x;
  const int gl = tid & (GS - 1);
  const int it = blockIdx.x * QPB + (tid >> 3);
  const int i = (int)sortedIdx[it];          // spatially-sorted query order

  const float R00 = st->Rc[0], R01 = st->Rc[1], R02 = st->Rc[2];
  const float R10 = st->Rc[3], R11 = st->Rc[4], R12 = st->Rc[5];
  const float R20 = st->Rc[6], R21 = st->Rc[7], R22 = st->Rc[8];
  const float t0 = st->tc[0], t1 = st->tc[1], t2 = st->tc[2];

  const float rx = ref[3*i], ry = ref[3*i+1], rz = ref[3*i+2];
  const float ax = rx - t0, ay = ry - t1, az = rz - t2;
  const float qx = R00*ax + R10*ay + R20*az;
  const float qy = R01*ax + R11*ay + R21*az;
  const float qz = R02*ax + R12*ay + R22*az;
  const int gx = cell1d(qx), gy = cell1d(qy), gz = cell1d(qz);

  unsigned long long bkey = 0xFFFFFFFFFFFFFFFFULL;
  for (int r = 1; r <= G; r++) {
    const int W = 2*r + 1, W2 = W * W, nc = W2 * W;
    for (int t = gl; t < nc; t += GS) {
      int tz = t / W2;
      int rm = t - tz * W2;
      int ty = rm / W;
      int tx = rm - ty * W;
      int cz = gz + tz - r, cy = gy + ty - r, cx = gx + tx - r;
      if ((unsigned)cx >= (unsigned)G || (unsigned)cy >= (unsigned)G ||
          (unsigned)cz >= (unsigned)G) continue;
      unsigned pc = gridPacked[(cz * G + cy) * G + cx];
      unsigned s0 = pc >> 8, n = pc & 255u;
      for (unsigned c = 0; c < n; c++) {
        float4 p = sortedPts[s0 + c];
        float ddx = qx - p.x, ddy = qy - p.y, ddz = qz - p.z;
        float d2 = fmaf(ddz, ddz, fmaf(ddy, ddy, ddx * ddx));
        unsigned long long key = ((unsigned long long)__float_as_uint(d2) << 32)
                               | (unsigned long long)__float_as_uint(p.w);
        bkey = key < bkey ? key : bkey;
      }
    }
    // group min across the 8 cooperating lanes
    #pragma unroll
    for (int off = 1; off < GS; off <<= 1) {
      unsigned long long o = __shfl_xor(bkey, off, 64);
      bkey = o < bkey ? o : bkey;
    }
    float best = __uint_as_float((unsigned)(bkey >> 32));  // NaN if none found yet
    // distance from q to nearest unscanned cell face (grid-edge faces excluded:
    // out-of-bbox points are clamped into edge cells, which the box covers)
    float dmin = 3.4e38f;
    if (gx - r > 0)     dmin = fminf(dmin, qx - (XMIN + (float)(gx - r) * CELL_H));
    if (gx + r < G - 1) dmin = fminf(dmin, (XMIN + (float)(gx + r + 1) * CELL_H) - qx);
    if (gy - r > 0)     dmin = fminf(dmin, qy - (XMIN + (float)(gy - r) * CELL_H));
    if (gy + r < G - 1) dmin = fminf(dmin, (XMIN + (float)(gy + r + 1) * CELL_H) - qy);
    if (gz - r > 0)     dmin = fminf(dmin, qz - (XMIN + (float)(gz - r) * CELL_H));
    if (gz + r < G - 1) dmin = fminf(dmin, (XMIN + (float)(gz + r + 1) * CELL_H) - qz);
    if (best <= dmin * dmin) break;        // NaN compare false -> keep expanding
  }
  const int j = (int)(unsigned)(bkey & 0xFFFFFFFFULL);

  // ---- point-to-plane residual + Jacobian (leader lane only; others zero) ----
  float Jv[6] = {0.f, 0.f, 0.f, 0.f, 0.f, 0.f};
  float rres = 0.f;
  if (gl == 0) {
    float nx0 = nrm[3*j], ny0 = nrm[3*j+1], nz0 = nrm[3*j+2];
    float sx = trg[3*j], sy = trg[3*j+1], sz = trg[3*j+2];
    float nx = R00*nx0 + R01*ny0 + R02*nz0;
    float ny = R10*nx0 + R11*ny0 + R12*nz0;
    float nz = R20*nx0 + R21*ny0 + R22*nz0;
    float pxx = R00*sx + R01*sy + R02*sz + t0;
    float pyy = R10*sx + R11*sy + R12*sz + t1;
    float pzz = R20*sx + R21*sy + R22*sz + t2;
    float dxx = rx - pxx, dyy = ry - pyy, dzz = rz - pzz;
    rres = nx*dxx + ny*dyy + nz*dzz;
    Jv[0] = ry*nz - rz*ny;
    Jv[1] = rz*nx - rx*nz;
    Jv[2] = rx*ny - ry*nx;
    Jv[3] = nx; Jv[4] = ny; Jv[5] = nz;
  }

  // double accumulation -> insensitive to scatter-order permutation
  double acc[28];
  int c21 = 0;
  #pragma unroll
  for (int a = 0; a < 6; a++)
    #pragma unroll
    for (int b = a; b < 6; b++)
      acc[c21++] = (double)Jv[a] * (double)Jv[b];
  #pragma unroll
  for (int a = 0; a < 6; a++) acc[21+a] = (double)Jv[a] * (double)rres;
  acc[27] = (double)rres * (double)rres;

  #pragma unroll
  for (int kk = 0; kk < 28; kk++) {
    double v = acc[kk];
    for (int off = 32; off; off >>= 1) v += __shfl_down(v, off);
    acc[kk] = v;
  }
  __shared__ double redD[4][28];
  int wave = tid >> 6, lane = tid & 63;
  if (lane == 0) {
    #pragma unroll
    for (int kk = 0; kk < 28; kk++) redD[wave][kk] = acc[kk];
  }
  __syncthreads();
  if (tid < 28)
    partials[tid * NEVAL + blockIdx.x] =
        redD[0][tid] + redD[1][tid] + redD[2][tid] + redD[3][tid];

  // ---- last-block-does-LM ----
  __shared__ bool last;
  __syncthreads();
  if (tid == 0) {
    __threadfence();
    unsigned old = atomicAdd(counter, 1u);
    last = (old == NEVAL - 1);
  }
  __syncthreads();
  if (!last) return;

  __threadfence();
  // fixed-order two-stage sum over 512 blocks (deterministic)
  __shared__ double red2[28][8];
  if (tid < 224) {
    int c = tid >> 3, s = tid & 7;
    double sum = 0.0;
    const double* pp = partials + c * NEVAL + s * 64;
    for (int b = 0; b < 64; b++) sum += pp[b];
    red2[c][s] = sum;
  }
  __syncthreads();
  __shared__ float tot[28];
  if (tid < 28) {
    double s = 0.0;
    #pragma unroll
    for (int k = 0; k < 8; k++) s += red2[tid][k];
    tot[tid] = (float)s;
  }
  __syncthreads();

  if (tid == 0) {
    atomicExch(counter, 0u);           // reset for next eval
    float Fn = tot[27];
    float mu, nu;

    if (mode == 0) {
      #pragma unroll
      for (int k = 0; k < 6; k++) st->x[k] = st->xc[k];
      #pragma unroll
      for (int k = 0; k < 21; k++) st->H[k] = tot[k];
      #pragma unroll
      for (int k = 0; k < 6; k++) st->g[k] = tot[21+k];
      st->F = Fn;
      float md = tot[0];
      md = fmaxf(md, tot[6]); md = fmaxf(md, tot[11]); md = fmaxf(md, tot[15]);
      md = fmaxf(md, tot[18]); md = fmaxf(md, tot[20]);
      mu = TAU_C * md;
      nu = 2.f;
    } else {
      mu = st->mu; nu = st->nu;
      float denom = 0.f;
      #pragma unroll
      for (int k = 0; k < 6; k++) denom += st->dx[k] * (mu * st->dx[k] - st->g[k]);
      if (fabsf(denom) < 1e-12f) denom = 1e-12f;
      float rho = (st->F - Fn) / denom;
      if (rho > 0.f) {
        #pragma unroll
        for (int k = 0; k < 6; k++) st->x[k] = st->xc[k];
        #pragma unroll
        for (int k = 0; k < 21; k++) st->H[k] = tot[k];
        #pragma unroll
        for (int k = 0; k < 6; k++) st->g[k] = tot[21+k];
        st->F = Fn;
        float tcube = 2.f * rho - 1.f;
        mu = mu * fmaxf(1.f / 3.f, 1.f - tcube * tcube * tcube);
        nu = 2.f;
      } else {
        mu = mu * nu;
        nu = 2.f * nu;
      }
    }
    st->mu = mu; st->nu = nu;

    if (mode < N_ITER) {
      // solve (H + mu I) d = -g ; SPD -> unpivoted Gauss, fully unrolled
      float A[6][7];
      int c21b = 0;
      #pragma unroll
      for (int a = 0; a < 6; a++)
        #pragma unroll
        for (int b = a; b < 6; b++) { A[a][b] = st->H[c21b]; A[b][a] = st->H[c21b]; c21b++; }
      #pragma unroll
      for (int a = 0; a < 6; a++) { A[a][a] += mu; A[a][6] = -st->g[a]; }
      #pragma unroll
      for (int col = 0; col < 6; col++) {
        float inv = 1.f / A[col][col];
        #pragma unroll
        for (int rI = 0; rI < 6; rI++) {
          if (rI > col) {
            float f = A[rI][col] * inv;
            #pragma unroll
            for (int cc = 0; cc < 7; cc++)
              if (cc >= col) A[rI][cc] -= f * A[col][cc];
          }
        }
      }
      float d[6];
      #pragma unroll
      for (int rI = 5; rI >= 0; rI--) {
        float s = A[rI][6];
        #pragma unroll
        for (int cc = 0; cc < 6; cc++)
          if (cc > rI) s -= A[rI][cc] * d[cc];
        d[rI] = s / A[rI][rI];
      }
      float Rn[9], tn[3];
      #pragma unroll
      for (int k = 0; k < 6; k++) { st->dx[k] = d[k]; st->xc[k] = st->x[k] + d[k]; }
      se3_exp_rt(st->xc, Rn, tn);
      #pragma unroll
      for (int k = 0; k < 9; k++) st->Rc[k] = Rn[k];
      #pragma unroll
      for (int k = 0; k < 3; k++) st->tc[k] = tn[k];
    } else {
      float Rn[9], tn[3];
      se3_exp_rt(st->x, Rn, tn);
      out[0] = Rn[0]; out[1] = Rn[1]; out[2]  = Rn[2]; out[3]  = tn[0];
      out[4] = Rn[3]; out[5] = Rn[4]; out[6]  = Rn[5]; out[7]  = tn[1];
      out[8] = Rn[6]; out[9] = Rn[7]; out[10] = Rn[8]; out[11] = tn[2];
      out[12] = 0.f; out[13] = 0.f; out[14] = 0.f; out[15] = 1.f;
      out[16] = st->F / (float)N_PTS;
    }
  }
}

extern "C" void kernel_launch(void* const* d_in, const int* in_sizes, int n_in,
                              void* d_out, int out_size, void* d_ws, size_t ws_size,
                              hipStream_t stream) {
  const float* ref = (const float*)d_in[0];
  const float* trg = (const float*)d_in[1];
  const float* nrm = (const float*)d_in[2];
  float* out = (float*)d_out;

  char* ws = (char*)d_ws;
  unsigned* count      = (unsigned*)(ws);                       // 442,368 B
  unsigned* gridPacked = (unsigned*)(ws + 442368);              // 442,368 B
  unsigned* cursor     = (unsigned*)(ws + 884736);              // 442,368 B
  unsigned* blockSums  = (unsigned*)(ws + 1327104);             // 2,048 B
  float4*   sortedPts  = (float4*)  (ws + 1329152);             // 262,144 B
  unsigned* sortedIdx  = (unsigned*)(ws + 1591296);             // 65,536 B
  double*   partials   = (double*)  (ws + 1656832);             // 114,688 B
  unsigned* counter    = (unsigned*)(ws + 1771520);
  State*    st         = (State*)   (ws + 1771584);

  // build grid over targets (once) + init LM state
  zero_kernel   <<<(NCELLS + 255) / 256, 256, 0, stream>>>(count, counter, st);
  count_kernel  <<<N_PTS / 256, 256, 0, stream>>>(trg, count);
  scan1_kernel  <<<NSCAN, 256, 0, stream>>>(count, cursor, blockSums);
  scan2_kernel  <<<1, 512, 0, stream>>>(blockSums);
  scan3_kernel  <<<NSCAN, 256, 0, stream>>>(count, cursor, blockSums, gridPacked);
  scatter_kernel<<<N_PTS / 256, 256, 0, stream>>>(trg, cursor, sortedPts, sortedIdx);

  for (int e = 0; e <= N_ITER; e++)
    eval_kernel<<<NEVAL, 256, 0, stream>>>(ref, trg, nrm, gridPacked, sortedPts,
                                           sortedIdx, st, partials, counter, out, e);
}